// Round 9
// baseline (297.548 us; speedup 1.0000x reference)
//
#include <hip/hip_runtime.h>

// ---------------------------------------------------------------------------
// relu linear attention, bf16-MFMA
//   q,k,v: [B=4][H=8][128][8192] fp32   out: [B][128][H][8192] fp32
//   p1: partial[bh][split][129][128] = sum_n v[d][n]*relu(k[e][n])
//       r5 indexing, restructured for TLP*MLP: 256thr/32KB-single-buffer LDS
//       (4 blocks/CU) x nsplit=32 (1024 blocks) = 16 waves/CU, with a 64-reg
//       load batch issued before compute and consumed after the barrier.
//   p2: reduce -> vk fp32 -> split to vk_hi/vk_lo bf16 (+ den row fp32)
//   p3: out[d][n] = (sum_e (vk_hi+vk_lo)[d][e]*relu(q)[e][n]) / den[n]
// ---------------------------------------------------------------------------

typedef __attribute__((ext_vector_type(8))) short short8;
typedef __attribute__((ext_vector_type(4))) float f32x4;

__device__ inline unsigned short f2bf(float f) {
    unsigned u = __float_as_uint(f);
    u += 0x7FFFu + ((u >> 16) & 1u);            // RNE
    return (unsigned short)(u >> 16);
}
__device__ inline float bf2f(unsigned short h) {
    return __uint_as_float(((unsigned)h) << 16);
}
__device__ inline unsigned pk2(float a, float b) {
    return (unsigned)f2bf(a) | ((unsigned)f2bf(b) << 16);
}

// ============================ pass 1 =======================================
// 256 thr (2x2 waves), out tile 128d x 128e; TN=64-n tiles, SINGLE 32KB buf.
// LDS: V bf16 [128][128B] @0, K @16384; swizzle byte ^ ((row&7)<<4).
__global__ __launch_bounds__(256, 4) void p1_vk(
    const float* __restrict__ K, const float* __restrict__ V,
    float* __restrict__ partial, int nsplit, int chunk)
{
    __shared__ char smem[32768];
    const int bh = blockIdx.y, split = blockIdx.x;
    const int t = threadIdx.x;
    const int lane = t & 63, w = t >> 6;
    const int dh = (w >> 1) << 6, eh = (w & 1) << 6;
    const int l15 = lane & 15, l4 = lane >> 4;
    const size_t base = (size_t)bh * (128 * 8192);
    const int n0 = split * chunk;
    const int rq = t >> 4;                       // 0..15
    const int cq = t & 15;                       // float4 col 0..15
    const int cw = (cq * 8) ^ ((rq & 7) << 4);   // swizzled byte col (writes)

    const float* Vb = V + base + (size_t)rq * 8192 + cq * 4 + n0;
    const float* Kb = K + base + (size_t)rq * 8192 + cq * 4 + n0;

    f32x4 acc[4][4];
#pragma unroll
    for (int i = 0; i < 4; ++i)
#pragma unroll
        for (int j = 0; j < 4; ++j)
            acc[i][j] = (f32x4){0.f, 0.f, 0.f, 0.f};
    float kp[8] = {0.f, 0.f, 0.f, 0.f, 0.f, 0.f, 0.f, 0.f};

    const int niter = chunk >> 6;
    float4 lv[8], lk[8];

    auto LOAD = [&](int it) {
        const int nt = it << 6;
#pragma unroll
        for (int i = 0; i < 8; ++i) {
            lv[i] = *(const float4*)(Vb + (size_t)(i << 4) * 8192 + nt);
            lk[i] = *(const float4*)(Kb + (size_t)(i << 4) * 8192 + nt);
        }
    };
    auto PACK = [&]() {
#pragma unroll
        for (int i = 0; i < 8; ++i) {
            const int row = (i << 4) + rq;
            *(uint2*)(smem + row * 128 + cw) =
                make_uint2(pk2(lv[i].x, lv[i].y), pk2(lv[i].z, lv[i].w));
            float4 kk = lk[i];
            kk.x = fmaxf(kk.x, 0.f); kk.y = fmaxf(kk.y, 0.f);
            kk.z = fmaxf(kk.z, 0.f); kk.w = fmaxf(kk.w, 0.f);
            kp[i] += (kk.x + kk.y) + (kk.z + kk.w);
            *(uint2*)(smem + 16384 + row * 128 + cw) =
                make_uint2(pk2(kk.x, kk.y), pk2(kk.z, kk.w));
        }
    };
    auto COMPUTE = [&]() {
        const char* bV = smem;
        const char* bK = smem + 16384;
#pragma unroll
        for (int sub = 0; sub < 2; ++sub) {
            short8 Bf[4];
#pragma unroll
            for (int j = 0; j < 4; ++j) {
                const int er = eh + (j << 4) + l15;
                Bf[j] = *(const short8*)(bK +
                        ((er * 128 + sub * 64 + l4 * 16) ^ ((er & 7) << 4)));
            }
#pragma unroll
            for (int i4 = 0; i4 < 4; ++i4) {
                const int dr = dh + (i4 << 4) + l15;
                const short8 Af = *(const short8*)(bV +
                        ((dr * 128 + sub * 64 + l4 * 16) ^ ((dr & 7) << 4)));
#pragma unroll
                for (int j = 0; j < 4; ++j)
                    acc[i4][j] = __builtin_amdgcn_mfma_f32_16x16x32_bf16(
                            Af, Bf[j], acc[i4][j], 0, 0, 0);
            }
        }
    };

    // prologue: tile 0
    LOAD(0);
    PACK();
    __syncthreads();

    for (int it = 0; it < niter; ++it) {
        if (it + 1 < niter) LOAD(it + 1);        // issue next batch (64 regs)
        __builtin_amdgcn_sched_barrier(0);       // keep loads above compute
        COMPUTE();                               // consume current LDS tile
        __syncthreads();                         // all waves done reading
        __builtin_amdgcn_sched_barrier(0);
        if (it + 1 < niter) {
            PACK();                              // first use of batch -> wait here
            __syncthreads();                     // tile ready
        }
    }
    __syncthreads();

    // den-row reduce via LDS overlay (first 8KB of smem, tile is dead)
    float* krd = (float*)smem;
#pragma unroll
    for (int i = 0; i < 8; ++i)
        krd[((i << 4) + rq) * 16 + cq] = kp[i];
    __syncthreads();

    float* p = partial + (size_t)(bh * nsplit + split) * 16512;
#pragma unroll
    for (int i = 0; i < 4; ++i)
#pragma unroll
        for (int j = 0; j < 4; ++j)
#pragma unroll
            for (int jj = 0; jj < 4; ++jj)
                p[(dh + (i << 4) + (l4 << 2) + jj) * 128 + eh + (j << 4) + l15] = acc[i][j][jj];
    if (t < 128) {
        float s = 0.f;
#pragma unroll
        for (int m = 0; m < 16; ++m) s += krd[t * 16 + m];
        p[16384 + t] = s;
    }
}

// ============================ pass 2 =======================================
__global__ __launch_bounds__(256) void p2_reduce(
    const float* __restrict__ partial, unsigned short* __restrict__ vkhi,
    unsigned short* __restrict__ vklo, float* __restrict__ vkden, int nsplit)
{
    const int t = blockIdx.x * 256 + threadIdx.x;
    if (t >= 32 * 129 * 128) return;
    const int bh = t / 16512, rc = t % 16512;
    const int d = rc >> 7, e = rc & 127;
    float s = 0.f;
    for (int i = 0; i < nsplit; ++i)
        s += partial[(size_t)(bh * nsplit + i) * 16512 + rc];
    if (d < 128) {
        const size_t off = (size_t)bh * 16384 + (e >> 5) * 4096 + d * 32 + (e & 31);
        const unsigned short h = f2bf(s);
        vkhi[off] = h;
        vklo[off] = f2bf(s - bf2f(h));
    } else {
        vkden[bh * 128 + e] = s;
    }
}

// ============================ pass 3 =======================================
#define VKH 0
#define VKL 10240
#define SQO 20480
#define DEN 40960
#define VKD 41984
__global__ __launch_bounds__(256, 2) void p3_out(
    const float* __restrict__ Q, const unsigned short* __restrict__ vkhi,
    const unsigned short* __restrict__ vklo, const float* __restrict__ vkden,
    float* __restrict__ out)
{
    __shared__ char smem[42496];
    const int bh = blockIdx.y;
    const int b = bh >> 3, h = bh & 7;
    const int n0 = blockIdx.x << 8;
    const int t = threadIdx.x;
    const int lane = t & 63, w = t >> 6;
    const int l15 = lane & 15, l4 = lane >> 4;
    const int wn = w << 6;

    if (t < 128) ((float*)(smem + VKD))[t] = vkden[bh * 128 + t];
    __syncthreads();

    const float* qb = Q + (size_t)bh * (128 * 8192) + n0 + t;   // this thread's n column
    const float* vkd = (const float*)(smem + VKD);
    const unsigned short* ghb = vkhi + (size_t)bh * 16384;
    const unsigned short* glb = vklo + (size_t)bh * 16384;

    f32x4 acc[8][4];
#pragma unroll
    for (int i = 0; i < 8; ++i)
#pragma unroll
        for (int j = 0; j < 4; ++j)
            acc[i][j] = (f32x4){0.f, 0.f, 0.f, 0.f};
    float den = 0.f;

    for (int ek = 0; ek < 4; ++ek) {
        const int e0 = ek << 5;
#pragma unroll
        for (int l = 0; l < 2; ++l) {
            const int s = t + (l << 8);
            const int d = s >> 2, c = s & 3;
            const int loff = d * 80 + c * 16;
            *(uint4*)(smem + VKH + loff) = *(const uint4*)(ghb + ek * 4096 + s * 8);
            *(uint4*)(smem + VKL + loff) = *(const uint4*)(glb + ek * 4096 + s * 8);
        }
#pragma unroll
        for (int sub = 0; sub < 4; ++sub) {
            const int j0 = e0 + (sub << 3);
            float vq[8];
#pragma unroll
            for (int m = 0; m < 8; ++m) vq[m] = qb[(size_t)(j0 + m) * 8192];
#pragma unroll
            for (int m = 0; m < 8; ++m) {
                vq[m] = fmaxf(vq[m], 0.f);
                den = fmaf(vkd[j0 + m], vq[m], den);
            }
            uint4 pq;
            pq.x = pk2(vq[0], vq[1]); pq.y = pk2(vq[2], vq[3]);
            pq.z = pk2(vq[4], vq[5]); pq.w = pk2(vq[6], vq[7]);
            *(uint4*)(smem + SQO + t * 80 + (sub << 4)) = pq;
        }
        __syncthreads();
        short8 Bf[4];
#pragma unroll
        for (int fn = 0; fn < 4; ++fn) {
            const int nr = wn + (fn << 4) + l15;
            Bf[fn] = *(const short8*)(smem + SQO + nr * 80 + l4 * 16);
        }
#pragma unroll
        for (int fd = 0; fd < 8; ++fd) {
            const int dr = (fd << 4) + l15;
            const short8 Ah = *(const short8*)(smem + VKH + dr * 80 + l4 * 16);
            const short8 Al = *(const short8*)(smem + VKL + dr * 80 + l4 * 16);
#pragma unroll
            for (int fn = 0; fn < 4; ++fn) {
                acc[fd][fn] = __builtin_amdgcn_mfma_f32_16x16x32_bf16(Ah, Bf[fn], acc[fd][fn], 0, 0, 0);
                acc[fd][fn] = __builtin_amdgcn_mfma_f32_16x16x32_bf16(Al, Bf[fn], acc[fd][fn], 0, 0, 0);
            }
        }
        __syncthreads();
    }

    ((float*)(smem + DEN))[t] = den;
    __syncthreads();
    float rden[4];
#pragma unroll
    for (int fn = 0; fn < 4; ++fn)
        rden[fn] = 1.f / ((const float*)(smem + DEN))[wn + (fn << 4) + l15];

#pragma unroll
    for (int fd = 0; fd < 8; ++fd) {
#pragma unroll
        for (int fn = 0; fn < 4; ++fn) {
            const int n = n0 + wn + (fn << 4) + l15;
#pragma unroll
            for (int jj = 0; jj < 4; ++jj) {
                const int d = (fd << 4) + (l4 << 2) + jj;
                out[(((size_t)b * 128 + d) * 8 + h) * 8192 + n] = acc[fd][fn][jj] * rden[fn];
            }
        }
    }
}

// ============================ launch =======================================
extern "C" void kernel_launch(void* const* d_in, const int* in_sizes, int n_in,
                              void* d_out, int out_size, void* d_ws, size_t ws_size,
                              hipStream_t stream)
{
    const float* q = (const float*)d_in[0];
    const float* k = (const float*)d_in[1];
    const float* v = (const float*)d_in[2];
    float* out = (float*)d_out;
    char* ws = (char*)d_ws;

    int nsplit = 32;
    while (nsplit > 1 &&
           ((size_t)32 * nsplit * 16512 * 4 + (size_t)32 * 16384 * 2 * 2 + 32 * 128 * 4) > ws_size)
        nsplit >>= 1;
    const int chunk = 8192 / nsplit;

    float* partial = (float*)ws;
    unsigned short* vkhi = (unsigned short*)(ws + (size_t)32 * nsplit * 16512 * 4);
    unsigned short* vklo = vkhi + 32 * 16384;
    float* vkden = (float*)(vklo + 32 * 16384);

    p1_vk<<<dim3(nsplit, 32), 256, 0, stream>>>(k, v, partial, nsplit, chunk);
    p2_reduce<<<(32 * 129 * 128 + 255) / 256, 256, 0, stream>>>(partial, vkhi, vklo, vkden, nsplit);
    p3_out<<<dim3(32, 32), 256, 0, stream>>>(q, vkhi, vklo, vkden, out);
}

// Round 10
// 172.698 us; speedup vs baseline: 1.7229x; 1.7229x over previous
//
#include <hip/hip_runtime.h>

// ---------------------------------------------------------------------------
// relu linear attention, bf16-MFMA
//   q,k,v: [B=4][H=8][128][8192] fp32   out: [B][128][H][8192] fp32
//   p1: partial[bh][split][129][128] = sum_n v[d][n]*relu(k[e][n])
//       TLP*MLP without spill: 512 thr (8 waves, acc 4x2 = 32 VGPR),
//       32-VGPR staging batch, single 32KB LDS buffer, 2 blocks/CU x
//       nsplit=32 -> 16 waves/CU.
//   p2: reduce -> vk fp32 -> split to vk_hi/vk_lo bf16 (+ den row fp32)
//   p3: out[d][n] = (sum_e (vk_hi+vk_lo)[d][e]*relu(q)[e][n]) / den[n]
// ---------------------------------------------------------------------------

typedef __attribute__((ext_vector_type(8))) short short8;
typedef __attribute__((ext_vector_type(4))) float f32x4;

__device__ inline unsigned short f2bf(float f) {
    unsigned u = __float_as_uint(f);
    u += 0x7FFFu + ((u >> 16) & 1u);            // RNE
    return (unsigned short)(u >> 16);
}
__device__ inline float bf2f(unsigned short h) {
    return __uint_as_float(((unsigned)h) << 16);
}
__device__ inline unsigned pk2(float a, float b) {
    return (unsigned)f2bf(a) | ((unsigned)f2bf(b) << 16);
}

// ============================ pass 1 =======================================
// 512 thr (8 waves: 2d x 4e), out tile 128d x 128e; TN=64-n tiles, 32KB buf.
// LDS: V bf16 [128 rows][128 B] @0, K @16384; swizzle byte ^ ((row&7)<<4).
__global__ __launch_bounds__(512, 4) void p1_vk(
    const float* __restrict__ K, const float* __restrict__ V,
    float* __restrict__ partial, int nsplit, int chunk)
{
    __shared__ char smem[32768];
    const int bh = blockIdx.y, split = blockIdx.x;
    const int t = threadIdx.x;
    const int lane = t & 63, w = t >> 6;
    const int dh = (w >> 2) << 6;               // 0,64
    const int eh = (w & 3) << 5;                // 0,32,64,96
    const int l15 = lane & 15, l4 = lane >> 4;
    const size_t base = (size_t)bh * (128 * 8192);
    const int n0 = split * chunk;
    const int rq = t >> 4;                       // staging base row 0..31
    const int cq = t & 15;                       // float4 col 0..15
    const int cw = (cq * 8) ^ ((rq & 7) << 4);   // swizzled byte col (rq&7 == row&7)

    const float* Vb = V + base + (size_t)rq * 8192 + cq * 4 + n0;
    const float* Kb = K + base + (size_t)rq * 8192 + cq * 4 + n0;

    f32x4 acc[4][2];
#pragma unroll
    for (int i = 0; i < 4; ++i)
#pragma unroll
        for (int j = 0; j < 2; ++j)
            acc[i][j] = (f32x4){0.f, 0.f, 0.f, 0.f};
    float kp[4] = {0.f, 0.f, 0.f, 0.f};

    const int niter = chunk >> 6;
    float4 lv[4], lk[4];                         // 32 VGPR batch

    auto LOAD = [&](int it) {
        const int nt = it << 6;
#pragma unroll
        for (int i = 0; i < 4; ++i) {
            lv[i] = *(const float4*)(Vb + (size_t)(i << 5) * 8192 + nt);
            lk[i] = *(const float4*)(Kb + (size_t)(i << 5) * 8192 + nt);
        }
    };
    auto PACK = [&]() {
#pragma unroll
        for (int i = 0; i < 4; ++i) {
            const int row = (i << 5) + rq;
            *(uint2*)(smem + row * 128 + cw) =
                make_uint2(pk2(lv[i].x, lv[i].y), pk2(lv[i].z, lv[i].w));
            float4 kk = lk[i];
            kk.x = fmaxf(kk.x, 0.f); kk.y = fmaxf(kk.y, 0.f);
            kk.z = fmaxf(kk.z, 0.f); kk.w = fmaxf(kk.w, 0.f);
            kp[i] += (kk.x + kk.y) + (kk.z + kk.w);
            *(uint2*)(smem + 16384 + row * 128 + cw) =
                make_uint2(pk2(kk.x, kk.y), pk2(kk.z, kk.w));
        }
    };
    auto COMPUTE = [&]() {
        const char* bV = smem;
        const char* bK = smem + 16384;
#pragma unroll
        for (int sub = 0; sub < 2; ++sub) {
            short8 Bf[2];
#pragma unroll
            for (int j = 0; j < 2; ++j) {
                const int er = eh + (j << 4) + l15;
                Bf[j] = *(const short8*)(bK +
                        ((er * 128 + sub * 64 + l4 * 16) ^ ((er & 7) << 4)));
            }
#pragma unroll
            for (int i4 = 0; i4 < 4; ++i4) {
                const int dr = dh + (i4 << 4) + l15;
                const short8 Af = *(const short8*)(bV +
                        ((dr * 128 + sub * 64 + l4 * 16) ^ ((dr & 7) << 4)));
#pragma unroll
                for (int j = 0; j < 2; ++j)
                    acc[i4][j] = __builtin_amdgcn_mfma_f32_16x16x32_bf16(
                            Af, Bf[j], acc[i4][j], 0, 0, 0);
            }
        }
    };

    // prologue: tile 0
    LOAD(0);
    PACK();
    __syncthreads();

    for (int it = 0; it < niter; ++it) {
        if (it + 1 < niter) LOAD(it + 1);        // issue next batch (32 regs)
        __builtin_amdgcn_sched_barrier(0);       // keep loads above compute
        COMPUTE();                               // consume current LDS tile
        __syncthreads();                         // all waves done reading
        __builtin_amdgcn_sched_barrier(0);
        if (it + 1 < niter) {
            PACK();                              // first use of batch waits here
            __syncthreads();                     // tile ready
        }
    }
    __syncthreads();

    // den-row reduce via LDS overlay (first 8KB, tile is dead)
    float* krd = (float*)smem;
#pragma unroll
    for (int i = 0; i < 4; ++i)
        krd[((i << 5) + rq) * 16 + cq] = kp[i];
    __syncthreads();

    float* p = partial + (size_t)(bh * nsplit + split) * 16512;
#pragma unroll
    for (int i = 0; i < 4; ++i)
#pragma unroll
        for (int j = 0; j < 2; ++j)
#pragma unroll
            for (int jj = 0; jj < 4; ++jj)
                p[(dh + (i << 4) + (l4 << 2) + jj) * 128 + eh + (j << 4) + l15] = acc[i][j][jj];
    if (t < 128) {
        float s = 0.f;
#pragma unroll
        for (int m = 0; m < 16; ++m) s += krd[t * 16 + m];
        p[16384 + t] = s;
    }
}

// ============================ pass 2 =======================================
__global__ __launch_bounds__(256) void p2_reduce(
    const float* __restrict__ partial, unsigned short* __restrict__ vkhi,
    unsigned short* __restrict__ vklo, float* __restrict__ vkden, int nsplit)
{
    const int t = blockIdx.x * 256 + threadIdx.x;
    if (t >= 32 * 129 * 128) return;
    const int bh = t / 16512, rc = t % 16512;
    const int d = rc >> 7, e = rc & 127;
    float s = 0.f;
    for (int i = 0; i < nsplit; ++i)
        s += partial[(size_t)(bh * nsplit + i) * 16512 + rc];
    if (d < 128) {
        const size_t off = (size_t)bh * 16384 + (e >> 5) * 4096 + d * 32 + (e & 31);
        const unsigned short h = f2bf(s);
        vkhi[off] = h;
        vklo[off] = f2bf(s - bf2f(h));
    } else {
        vkden[bh * 128 + e] = s;
    }
}

// ============================ pass 3 =======================================
#define VKH 0
#define VKL 10240
#define SQO 20480
#define DEN 40960
#define VKD 41984
__global__ __launch_bounds__(256, 2) void p3_out(
    const float* __restrict__ Q, const unsigned short* __restrict__ vkhi,
    const unsigned short* __restrict__ vklo, const float* __restrict__ vkden,
    float* __restrict__ out)
{
    __shared__ char smem[42496];
    const int bh = blockIdx.y;
    const int b = bh >> 3, h = bh & 7;
    const int n0 = blockIdx.x << 8;
    const int t = threadIdx.x;
    const int lane = t & 63, w = t >> 6;
    const int l15 = lane & 15, l4 = lane >> 4;
    const int wn = w << 6;

    if (t < 128) ((float*)(smem + VKD))[t] = vkden[bh * 128 + t];
    __syncthreads();

    const float* qb = Q + (size_t)bh * (128 * 8192) + n0 + t;   // this thread's n column
    const float* vkd = (const float*)(smem + VKD);
    const unsigned short* ghb = vkhi + (size_t)bh * 16384;
    const unsigned short* glb = vklo + (size_t)bh * 16384;

    f32x4 acc[8][4];
#pragma unroll
    for (int i = 0; i < 8; ++i)
#pragma unroll
        for (int j = 0; j < 4; ++j)
            acc[i][j] = (f32x4){0.f, 0.f, 0.f, 0.f};
    float den = 0.f;

    for (int ek = 0; ek < 4; ++ek) {
        const int e0 = ek << 5;
#pragma unroll
        for (int l = 0; l < 2; ++l) {
            const int s = t + (l << 8);
            const int d = s >> 2, c = s & 3;
            const int loff = d * 80 + c * 16;
            *(uint4*)(smem + VKH + loff) = *(const uint4*)(ghb + ek * 4096 + s * 8);
            *(uint4*)(smem + VKL + loff) = *(const uint4*)(glb + ek * 4096 + s * 8);
        }
#pragma unroll
        for (int sub = 0; sub < 4; ++sub) {
            const int j0 = e0 + (sub << 3);
            float vq[8];
#pragma unroll
            for (int m = 0; m < 8; ++m) vq[m] = qb[(size_t)(j0 + m) * 8192];
#pragma unroll
            for (int m = 0; m < 8; ++m) {
                vq[m] = fmaxf(vq[m], 0.f);
                den = fmaf(vkd[j0 + m], vq[m], den);
            }
            uint4 pq;
            pq.x = pk2(vq[0], vq[1]); pq.y = pk2(vq[2], vq[3]);
            pq.z = pk2(vq[4], vq[5]); pq.w = pk2(vq[6], vq[7]);
            *(uint4*)(smem + SQO + t * 80 + (sub << 4)) = pq;
        }
        __syncthreads();
        short8 Bf[4];
#pragma unroll
        for (int fn = 0; fn < 4; ++fn) {
            const int nr = wn + (fn << 4) + l15;
            Bf[fn] = *(const short8*)(smem + SQO + nr * 80 + l4 * 16);
        }
#pragma unroll
        for (int fd = 0; fd < 8; ++fd) {
            const int dr = (fd << 4) + l15;
            const short8 Ah = *(const short8*)(smem + VKH + dr * 80 + l4 * 16);
            const short8 Al = *(const short8*)(smem + VKL + dr * 80 + l4 * 16);
#pragma unroll
            for (int fn = 0; fn < 4; ++fn) {
                acc[fd][fn] = __builtin_amdgcn_mfma_f32_16x16x32_bf16(Ah, Bf[fn], acc[fd][fn], 0, 0, 0);
                acc[fd][fn] = __builtin_amdgcn_mfma_f32_16x16x32_bf16(Al, Bf[fn], acc[fd][fn], 0, 0, 0);
            }
        }
        __syncthreads();
    }

    ((float*)(smem + DEN))[t] = den;
    __syncthreads();
    float rden[4];
#pragma unroll
    for (int fn = 0; fn < 4; ++fn)
        rden[fn] = 1.f / ((const float*)(smem + DEN))[wn + (fn << 4) + l15];

#pragma unroll
    for (int fd = 0; fd < 8; ++fd) {
#pragma unroll
        for (int fn = 0; fn < 4; ++fn) {
            const int n = n0 + wn + (fn << 4) + l15;
#pragma unroll
            for (int jj = 0; jj < 4; ++jj) {
                const int d = (fd << 4) + (l4 << 2) + jj;
                out[(((size_t)b * 128 + d) * 8 + h) * 8192 + n] = acc[fd][fn][jj] * rden[fn];
            }
        }
    }
}

// ============================ launch =======================================
extern "C" void kernel_launch(void* const* d_in, const int* in_sizes, int n_in,
                              void* d_out, int out_size, void* d_ws, size_t ws_size,
                              hipStream_t stream)
{
    const float* q = (const float*)d_in[0];
    const float* k = (const float*)d_in[1];
    const float* v = (const float*)d_in[2];
    float* out = (float*)d_out;
    char* ws = (char*)d_ws;

    int nsplit = 32;
    while (nsplit > 1 &&
           ((size_t)32 * nsplit * 16512 * 4 + (size_t)32 * 16384 * 2 * 2 + 32 * 128 * 4) > ws_size)
        nsplit >>= 1;
    const int chunk = 8192 / nsplit;

    float* partial = (float*)ws;
    unsigned short* vkhi = (unsigned short*)(ws + (size_t)32 * nsplit * 16512 * 4);
    unsigned short* vklo = vkhi + 32 * 16384;
    float* vkden = (float*)(vklo + 32 * 16384);

    p1_vk<<<dim3(nsplit, 32), 512, 0, stream>>>(k, v, partial, nsplit, chunk);
    p2_reduce<<<(32 * 129 * 128 + 255) / 256, 256, 0, stream>>>(partial, vkhi, vklo, vkden, nsplit);
    p3_out<<<dim3(32, 32), 256, 0, stream>>>(q, vkhi, vklo, vkden, out);
}